// Round 4
// baseline (1233.229 us; speedup 1.0000x reference)
//
#include <hip/hip_runtime.h>
#include <hip/hip_bf16.h>
#include <hip/hip_cooperative_groups.h>

namespace cg = cooperative_groups;

#define DD 128
#define TM 64
#define LD 136        // padded LDS row stride (bf16 elems)
#define SB 128        // scan blocks (fallback path)
#define GRID 1024     // cooperative grid: 4 blocks/CU on 256 CUs
#define BLK 256

typedef short bf16x8 __attribute__((ext_vector_type(8)));
typedef float f32x4  __attribute__((ext_vector_type(4)));

__device__ __forceinline__ unsigned short f2bf(float f) {
  unsigned int u = __float_as_uint(f);
  u += 0x7FFFu + ((u >> 16) & 1u);   // RNE
  return (unsigned short)(u >> 16);
}
__device__ __forceinline__ unsigned int pack2(float lo, float hi) {
  return (unsigned int)f2bf(lo) | ((unsigned int)f2bf(hi) << 16);
}
__device__ __forceinline__ float bf2f(unsigned short u) {
  union { unsigned int i; float f; } x; x.i = ((unsigned int)u) << 16; return x.f;
}

// ===================== fused cooperative pipeline =====================
__global__ __launch_bounds__(BLK, 4) void k_fused(
    const float* feat, const int* eidx,
    const float* w1, const float* b1, const float* w2, const float* b2,
    const float* gamma, const float* beta, float* out,
    unsigned short* wbf1, unsigned short* wbf2,
    int* cnt, int* ofs, int* cur, int* csr, int* bsum, int* bofs,
    float* partial, float* scsh, unsigned short* hbuf,
    int nrows, int ne, int ntiles)
{
  cg::grid_group grid = cg::this_grid();
  __shared__ __align__(16) unsigned short smem[2 * TM * LD];
  unsigned short* ldsH  = smem;
  unsigned short* ldsH2 = smem + TM * LD;
  int*   red  = reinterpret_cast<int*>(smem);
  float* fred = reinterpret_cast<float*>(smem);

  const int tid = threadIdx.x;
  const int b   = blockIdx.x;
  const int gt  = b * BLK + tid;
  const int GT  = GRID * BLK;          // 262144

  // ---- phase 0: zero cnt + convert weights to bf16 ----
  for (int i = gt; i < nrows; i += GT) cnt[i] = 0;
  for (int i = gt; i < DD * DD; i += GT) { wbf1[i] = f2bf(w1[i]); wbf2[i] = f2bf(w2[i]); }
  grid.sync();

  // ---- phase 1: degree histogram ----
  for (int e = gt; e < ne; e += GT) atomicAdd(&cnt[eidx[ne + e]], 1);
  grid.sync();

  const int chunk = (nrows + GRID - 1) / GRID;   // 98
  // ---- phase 2a: per-block chunk sums ----
  {
    int blo = b * chunk, bhi = min(nrows, blo + chunk);
    int s = 0;
    for (int i = blo + tid; i < bhi; i += BLK) s += cnt[i];
    red[tid] = s;
    __syncthreads();
    for (int off = 128; off; off >>= 1) {
      if (tid < off) red[tid] += red[tid + off];
      __syncthreads();
    }
    if (tid == 0) bsum[b] = red[0];
    __syncthreads();
  }
  grid.sync();

  // ---- phase 2b: block 0 scans bsum[GRID] -> bofs; ofs[nrows] = total ----
  if (b == 0) {
    int v[4]; int ts = 0;
    for (int k = 0; k < 4; ++k) { v[k] = bsum[tid * 4 + k]; ts += v[k]; }
    red[tid] = ts;
    __syncthreads();
    for (int off = 1; off < BLK; off <<= 1) {
      int q = (tid >= off) ? red[tid - off] : 0;
      __syncthreads();
      red[tid] += q;
      __syncthreads();
    }
    int run = red[tid] - ts;   // exclusive
    for (int k = 0; k < 4; ++k) { bofs[tid * 4 + k] = run; run += v[k]; }
    if (tid == BLK - 1) ofs[nrows] = red[BLK - 1];
  }
  grid.sync();

  // ---- phase 2c: per-block exclusive scan of chunk -> ofs, cur ----
  {
    int blo = b * chunk, bhi = min(nrows, blo + chunk);
    int tch = (chunk + BLK - 1) / BLK;  // 1
    int lo = blo + tid * tch, hi = min(bhi, lo + tch);
    int s = 0;
    for (int i = lo; i < hi; ++i) s += cnt[i];
    red[tid] = s;
    __syncthreads();
    for (int off = 1; off < BLK; off <<= 1) {
      int q = (tid >= off) ? red[tid - off] : 0;
      __syncthreads();
      red[tid] += q;
      __syncthreads();
    }
    int run = bofs[b] + red[tid] - s;
    for (int i = lo; i < hi; ++i) { int c = cnt[i]; ofs[i] = run; cur[i] = run; run += c; }
  }
  grid.sync();

  // ---- phase 3: fill CSR ----
  for (int e = gt; e < ne; e += GT) {
    int pos = atomicAdd(&cur[eidx[ne + e]], 1);
    csr[pos] = eidx[e];
  }
  grid.sync();

  // ---- phase 4: gather-aggregate h = x + sum(neighbors) -> hbuf bf16 ----
  for (int t = gt; t < nrows * 16; t += GT) {
    int row = t >> 4;
    int c = (t & 15) * 8;
    const float* fr = feat + (long long)row * DD + c;
    float4 a0 = *reinterpret_cast<const float4*>(fr);
    float4 b0 = *reinterpret_cast<const float4*>(fr + 4);
    float4 a1 = make_float4(0.f, 0.f, 0.f, 0.f);
    float4 b1v = make_float4(0.f, 0.f, 0.f, 0.f);
    int o0 = ofs[row], o1 = ofs[row + 1];
    int j = o0;
    for (; j + 2 <= o1; j += 2) {
      const float* f0 = feat + (long long)csr[j]     * DD + c;
      const float* f1 = feat + (long long)csr[j + 1] * DD + c;
      float4 x0 = *reinterpret_cast<const float4*>(f0);
      float4 y0 = *reinterpret_cast<const float4*>(f0 + 4);
      float4 x1 = *reinterpret_cast<const float4*>(f1);
      float4 y1 = *reinterpret_cast<const float4*>(f1 + 4);
      a0.x += x0.x; a0.y += x0.y; a0.z += x0.z; a0.w += x0.w;
      b0.x += y0.x; b0.y += y0.y; b0.z += y0.z; b0.w += y0.w;
      a1.x += x1.x; a1.y += x1.y; a1.z += x1.z; a1.w += x1.w;
      b1v.x += y1.x; b1v.y += y1.y; b1v.z += y1.z; b1v.w += y1.w;
    }
    if (j < o1) {
      const float* f0 = feat + (long long)csr[j] * DD + c;
      float4 x0 = *reinterpret_cast<const float4*>(f0);
      float4 y0 = *reinterpret_cast<const float4*>(f0 + 4);
      a0.x += x0.x; a0.y += x0.y; a0.z += x0.z; a0.w += x0.w;
      b0.x += y0.x; b0.y += y0.y; b0.z += y0.z; b0.w += y0.w;
    }
    a0.x += a1.x; a0.y += a1.y; a0.z += a1.z; a0.w += a1.w;
    b0.x += b1v.x; b0.y += b1v.y; b0.z += b1v.z; b0.w += b1v.w;
    uint4 u;
    u.x = pack2(a0.x, a0.y); u.y = pack2(a0.z, a0.w);
    u.z = pack2(b0.x, b0.y); u.w = pack2(b0.z, b0.w);
    *reinterpret_cast<uint4*>(hbuf + (long long)row * DD + c) = u;
  }
  grid.sync();

  // ---- phase 5: tiled MLP (bf16 MFMA), in-place hbuf, per-block BN partials ----
  {
    const int wave = tid >> 6, lane = tid & 63;
    const int q = lane >> 4, l16 = lane & 15;
    const int col0 = wave * 32;

    bf16x8 bw1[2][4], bw2[2][4];
    float bias1[2], bias2[2];
    for (int n = 0; n < 2; ++n) {
      int jc = col0 + n * 16 + l16;
      bias1[n] = b1[jc];
      bias2[n] = b2[jc];
      for (int kk = 0; kk < 4; ++kk) {
        bw1[n][kk] = *reinterpret_cast<const bf16x8*>(wbf1 + jc * DD + kk * 32 + q * 8);
        bw2[n][kk] = *reinterpret_cast<const bf16x8*>(wbf2 + jc * DD + kk * 32 + q * 8);
      }
    }

    float fs[2] = {0.f, 0.f}, fs2[2] = {0.f, 0.f};

    for (int tile = b; tile < ntiles; tile += GRID) {
      const int row0 = tile * TM;

      for (int it = 0; it < 4; ++it) {
        int idx = it * 2048 + tid * 8;
        int r = idx >> 7, c = idx & 127;
        int row = row0 + r;
        uint4 u = make_uint4(0u, 0u, 0u, 0u);
        if (row < nrows)
          u = *reinterpret_cast<const uint4*>(hbuf + (long long)row * DD + c);
        *reinterpret_cast<uint4*>(&ldsH[r * LD + c]) = u;
      }
      __syncthreads();

      f32x4 acc[4][2];
      const f32x4 zero = {0.f, 0.f, 0.f, 0.f};
      for (int m = 0; m < 4; ++m) for (int n = 0; n < 2; ++n) acc[m][n] = zero;

      for (int kk = 0; kk < 4; ++kk) {
        bf16x8 aF[4];
        for (int m = 0; m < 4; ++m)
          aF[m] = *reinterpret_cast<const bf16x8*>(&ldsH[(m * 16 + l16) * LD + kk * 32 + q * 8]);
        for (int m = 0; m < 4; ++m)
          for (int n = 0; n < 2; ++n)
            acc[m][n] = __builtin_amdgcn_mfma_f32_16x16x32_bf16(aF[m], bw1[n][kk], acc[m][n], 0, 0, 0);
      }

      for (int m = 0; m < 4; ++m)
        for (int n = 0; n < 2; ++n)
          for (int r = 0; r < 4; ++r) {
            float v = fmaxf(acc[m][n][r] + bias1[n], 0.f);
            ldsH2[(m * 16 + q * 4 + r) * LD + (col0 + n * 16 + l16)] = f2bf(v);
          }
      __syncthreads();

      for (int m = 0; m < 4; ++m) for (int n = 0; n < 2; ++n) acc[m][n] = zero;

      for (int kk = 0; kk < 4; ++kk) {
        bf16x8 aF[4];
        for (int m = 0; m < 4; ++m)
          aF[m] = *reinterpret_cast<const bf16x8*>(&ldsH2[(m * 16 + l16) * LD + kk * 32 + q * 8]);
        for (int m = 0; m < 4; ++m)
          for (int n = 0; n < 2; ++n)
            acc[m][n] = __builtin_amdgcn_mfma_f32_16x16x32_bf16(aF[m], bw2[n][kk], acc[m][n], 0, 0, 0);
      }

      for (int m = 0; m < 4; ++m)
        for (int n = 0; n < 2; ++n) {
          int col = col0 + n * 16 + l16;
          for (int r = 0; r < 4; ++r) {
            int rl = m * 16 + q * 4 + r;
            float v = fmaxf(acc[m][n][r] + bias2[n], 0.f);
            ldsH[rl * LD + col] = f2bf(v);
            if (row0 + rl < nrows) { fs[n] += v; fs2[n] += v * v; }
          }
        }
      __syncthreads();

      for (int it = 0; it < 4; ++it) {
        int idx = it * 2048 + tid * 8;
        int r = idx >> 7, c = idx & 127;
        int row = row0 + r;
        if (row < nrows)
          *reinterpret_cast<uint4*>(hbuf + (long long)row * DD + c) =
              *reinterpret_cast<const uint4*>(&ldsH[r * LD + c]);
      }
      __syncthreads();
    }

    for (int off = 16; off < 64; off <<= 1)
      for (int n = 0; n < 2; ++n) {
        fs[n]  += __shfl_xor(fs[n], off);
        fs2[n] += __shfl_xor(fs2[n], off);
      }
    if (q == 0) {
      float* pb = partial + (long long)b * 256;
      for (int n = 0; n < 2; ++n) {
        int col = col0 + n * 16 + l16;
        pb[col]       = fs[n];
        pb[128 + col] = fs2[n];
      }
    }
  }
  grid.sync();

  // ---- phase 6: reduce partials -> scsh (one block per column) ----
  if (b < 128) {
    int c = b;
    float s = 0.f, s2 = 0.f;
    for (int r = tid; r < GRID; r += BLK) {
      s  += partial[(long long)r * 256 + c];
      s2 += partial[(long long)r * 256 + 128 + c];
    }
    fred[tid] = s; fred[BLK + tid] = s2;
    __syncthreads();
    for (int off = 128; off; off >>= 1) {
      if (tid < off) { fred[tid] += fred[tid + off]; fred[BLK + tid] += fred[BLK + tid + off]; }
      __syncthreads();
    }
    if (tid == 0) {
      float mean = fred[0] / (float)nrows;
      float var  = fmaxf(fred[BLK] / (float)nrows - mean * mean, 0.f);
      float inv  = rsqrtf(var + 1e-5f);
      float sc   = gamma[c] * inv;
      scsh[c]       = sc;
      scsh[128 + c] = beta[c] - mean * sc;
    }
  }
  grid.sync();

  // ---- phase 7: BN apply, bf16 hbuf -> fp32 out ----
  {
    long long total8 = (long long)nrows * DD / 8;
    for (long long t = gt; t < total8; t += GT) {
      int c0 = (int)((t * 8) & 127);
      float4 sa = *reinterpret_cast<const float4*>(scsh + c0);
      float4 sb = *reinterpret_cast<const float4*>(scsh + c0 + 4);
      float4 ha = *reinterpret_cast<const float4*>(scsh + 128 + c0);
      float4 hb = *reinterpret_cast<const float4*>(scsh + 132 + c0);
      uint4 u = *reinterpret_cast<const uint4*>(hbuf + t * 8);
      float4 a, bb;
      a.x  = bf2f((unsigned short)(u.x & 0xFFFF)) * sa.x + ha.x;
      a.y  = bf2f((unsigned short)(u.x >> 16))    * sa.y + ha.y;
      a.z  = bf2f((unsigned short)(u.y & 0xFFFF)) * sa.z + ha.z;
      a.w  = bf2f((unsigned short)(u.y >> 16))    * sa.w + ha.w;
      bb.x = bf2f((unsigned short)(u.z & 0xFFFF)) * sb.x + hb.x;
      bb.y = bf2f((unsigned short)(u.z >> 16))    * sb.y + hb.y;
      bb.z = bf2f((unsigned short)(u.w & 0xFFFF)) * sb.z + hb.z;
      bb.w = bf2f((unsigned short)(u.w >> 16))    * sb.w + hb.w;
      float* of = out + t * 8;
      *reinterpret_cast<float4*>(of)     = a;
      *reinterpret_cast<float4*>(of + 4) = bb;
    }
  }
}

// ===================== fallback multi-kernel path (round-3) =====================
__global__ __launch_bounds__(256) void k_prep(const float* __restrict__ w1,
                                              const float* __restrict__ w2,
                                              unsigned short* __restrict__ wbf1,
                                              unsigned short* __restrict__ wbf2) {
  int i = blockIdx.x * 256 + threadIdx.x;
  if (i < DD * DD) { wbf1[i] = f2bf(w1[i]); wbf2[i] = f2bf(w2[i]); }
}

__global__ __launch_bounds__(256) void k_hist(const int* __restrict__ ei, int* __restrict__ cnt,
                                              int ne) {
  int e = blockIdx.x * 256 + threadIdx.x;
  if (e < ne) atomicAdd(&cnt[ei[ne + e]], 1);
}

__global__ __launch_bounds__(256) void k_scan1(const int* __restrict__ cnt,
                                               int* __restrict__ bsum, int n) {
  __shared__ int red[256];
  int b = blockIdx.x, t = threadIdx.x;
  int chunk = (n + SB - 1) / SB;
  int lo = b * chunk, hi = min(n, lo + chunk);
  int s = 0;
  for (int i = lo + t; i < hi; i += 256) s += cnt[i];
  red[t] = s;
  __syncthreads();
  for (int off = 128; off; off >>= 1) {
    if (t < off) red[t] += red[t + off];
    __syncthreads();
  }
  if (t == 0) bsum[b] = red[0];
}

__global__ __launch_bounds__(SB) void k_scan2(const int* __restrict__ bsum,
                                              int* __restrict__ bofs,
                                              int* __restrict__ ofs, int n) {
  __shared__ int tmp[SB];
  int t = threadIdx.x;
  int mine = bsum[t];
  tmp[t] = mine;
  __syncthreads();
  for (int off = 1; off < SB; off <<= 1) {
    int v = (t >= off) ? tmp[t - off] : 0;
    __syncthreads();
    tmp[t] += v;
    __syncthreads();
  }
  bofs[t] = tmp[t] - mine;
  if (t == SB - 1) ofs[n] = tmp[t];
}

__global__ __launch_bounds__(256) void k_scan3(const int* __restrict__ cnt,
                                               const int* __restrict__ bofs,
                                               int* __restrict__ ofs, int* __restrict__ cur,
                                               int n) {
  __shared__ int red[256];
  int b = blockIdx.x, t = threadIdx.x;
  int chunk  = (n + SB - 1) / SB;
  int tchunk = (chunk + 255) / 256;
  int blo = b * chunk, bhi = min(n, blo + chunk);
  int lo = blo + t * tchunk, hi = min(bhi, lo + tchunk);
  int s = 0;
  for (int i = lo; i < hi; ++i) s += cnt[i];
  int mine = s;
  red[t] = s;
  __syncthreads();
  for (int off = 1; off < 256; off <<= 1) {
    int v = (t >= off) ? red[t - off] : 0;
    __syncthreads();
    red[t] += v;
    __syncthreads();
  }
  int run = bofs[b] + red[t] - mine;
  for (int i = lo; i < hi; ++i) {
    int c = cnt[i];
    ofs[i] = run; cur[i] = run;
    run += c;
  }
}

__global__ __launch_bounds__(256) void k_fill(const int* __restrict__ ei, int* __restrict__ cur,
                                              int* __restrict__ csr, int ne) {
  int e = blockIdx.x * 256 + threadIdx.x;
  if (e >= ne) return;
  int pos = atomicAdd(&cur[ei[ne + e]], 1);
  csr[pos] = ei[e];
}

__global__ __launch_bounds__(256) void k_agg(
    const float* __restrict__ feat, const int* __restrict__ ofs, const int* __restrict__ csr,
    unsigned short* __restrict__ agg, int nrows)
{
  int t = blockIdx.x * 256 + threadIdx.x;
  int row = t >> 4;
  if (row >= nrows) return;
  int c = (t & 15) * 8;
  const float* fr = feat + (long long)row * DD + c;
  float4 a0 = *reinterpret_cast<const float4*>(fr);
  float4 b0 = *reinterpret_cast<const float4*>(fr + 4);
  float4 a1 = make_float4(0.f, 0.f, 0.f, 0.f);
  float4 b1 = make_float4(0.f, 0.f, 0.f, 0.f);
  int o0 = ofs[row], o1 = ofs[row + 1];
  int j = o0;
  for (; j + 2 <= o1; j += 2) {
    const float* f0 = feat + (long long)csr[j]     * DD + c;
    const float* f1 = feat + (long long)csr[j + 1] * DD + c;
    float4 x0 = *reinterpret_cast<const float4*>(f0);
    float4 y0 = *reinterpret_cast<const float4*>(f0 + 4);
    float4 x1 = *reinterpret_cast<const float4*>(f1);
    float4 y1 = *reinterpret_cast<const float4*>(f1 + 4);
    a0.x += x0.x; a0.y += x0.y; a0.z += x0.z; a0.w += x0.w;
    b0.x += y0.x; b0.y += y0.y; b0.z += y0.z; b0.w += y0.w;
    a1.x += x1.x; a1.y += x1.y; a1.z += x1.z; a1.w += x1.w;
    b1.x += y1.x; b1.y += y1.y; b1.z += y1.z; b1.w += y1.w;
  }
  if (j < o1) {
    const float* f0 = feat + (long long)csr[j] * DD + c;
    float4 x0 = *reinterpret_cast<const float4*>(f0);
    float4 y0 = *reinterpret_cast<const float4*>(f0 + 4);
    a0.x += x0.x; a0.y += x0.y; a0.z += x0.z; a0.w += x0.w;
    b0.x += y0.x; b0.y += y0.y; b0.z += y0.z; b0.w += y0.w;
  }
  a0.x += a1.x; a0.y += a1.y; a0.z += a1.z; a0.w += a1.w;
  b0.x += b1.x; b0.y += b1.y; b0.z += b1.z; b0.w += b1.w;
  uint4 u;
  u.x = pack2(a0.x, a0.y); u.y = pack2(a0.z, a0.w);
  u.z = pack2(b0.x, b0.y); u.w = pack2(b0.z, b0.w);
  *reinterpret_cast<uint4*>(agg + (long long)row * DD + c) = u;
}

__global__ __launch_bounds__(256) void k_mlp(
    unsigned short* hb,
    const unsigned short* __restrict__ wbf1, const float* __restrict__ b1,
    const unsigned short* __restrict__ wbf2, const float* __restrict__ b2,
    float* __restrict__ partial, int nrows, int ntiles)
{
  __shared__ unsigned short ldsH[TM * LD];
  __shared__ unsigned short ldsH2[TM * LD];
  const int tid  = threadIdx.x;
  const int wave = tid >> 6, lane = tid & 63;
  const int q = lane >> 4, l16 = lane & 15;
  const int col0 = wave * 32;

  bf16x8 bw1[2][4], bw2[2][4];
  float bias1[2], bias2[2];
  for (int n = 0; n < 2; ++n) {
    int jc = col0 + n * 16 + l16;
    bias1[n] = b1[jc];
    bias2[n] = b2[jc];
    for (int kk = 0; kk < 4; ++kk) {
      bw1[n][kk] = *reinterpret_cast<const bf16x8*>(wbf1 + jc * DD + kk * 32 + q * 8);
      bw2[n][kk] = *reinterpret_cast<const bf16x8*>(wbf2 + jc * DD + kk * 32 + q * 8);
    }
  }

  float fs[2] = {0.f, 0.f}, fs2[2] = {0.f, 0.f};

  for (int tile = blockIdx.x; tile < ntiles; tile += GRID) {
    const int row0 = tile * TM;

    for (int it = 0; it < 4; ++it) {
      int idx = it * 2048 + tid * 8;
      int r = idx >> 7, c = idx & 127;
      int row = row0 + r;
      uint4 u = make_uint4(0u, 0u, 0u, 0u);
      if (row < nrows)
        u = *reinterpret_cast<const uint4*>(hb + (long long)row * DD + c);
      *reinterpret_cast<uint4*>(&ldsH[r * LD + c]) = u;
    }
    __syncthreads();

    f32x4 acc[4][2];
    const f32x4 zero = {0.f, 0.f, 0.f, 0.f};
    for (int m = 0; m < 4; ++m) for (int n = 0; n < 2; ++n) acc[m][n] = zero;

    for (int kk = 0; kk < 4; ++kk) {
      bf16x8 aF[4];
      for (int m = 0; m < 4; ++m)
        aF[m] = *reinterpret_cast<const bf16x8*>(&ldsH[(m * 16 + l16) * LD + kk * 32 + q * 8]);
      for (int m = 0; m < 4; ++m)
        for (int n = 0; n < 2; ++n)
          acc[m][n] = __builtin_amdgcn_mfma_f32_16x16x32_bf16(aF[m], bw1[n][kk], acc[m][n], 0, 0, 0);
    }

    for (int m = 0; m < 4; ++m)
      for (int n = 0; n < 2; ++n)
        for (int r = 0; r < 4; ++r) {
          float v = fmaxf(acc[m][n][r] + bias1[n], 0.f);
          ldsH2[(m * 16 + q * 4 + r) * LD + (col0 + n * 16 + l16)] = f2bf(v);
        }
    __syncthreads();

    for (int m = 0; m < 4; ++m) for (int n = 0; n < 2; ++n) acc[m][n] = zero;

    for (int kk = 0; kk < 4; ++kk) {
      bf16x8 aF[4];
      for (int m = 0; m < 4; ++m)
        aF[m] = *reinterpret_cast<const bf16x8*>(&ldsH2[(m * 16 + l16) * LD + kk * 32 + q * 8]);
      for (int m = 0; m < 4; ++m)
        for (int n = 0; n < 2; ++n)
          acc[m][n] = __builtin_amdgcn_mfma_f32_16x16x32_bf16(aF[m], bw2[n][kk], acc[m][n], 0, 0, 0);
    }

    for (int m = 0; m < 4; ++m)
      for (int n = 0; n < 2; ++n) {
        int col = col0 + n * 16 + l16;
        for (int r = 0; r < 4; ++r) {
          int rl = m * 16 + q * 4 + r;
          float v = fmaxf(acc[m][n][r] + bias2[n], 0.f);
          ldsH[rl * LD + col] = f2bf(v);
          if (row0 + rl < nrows) { fs[n] += v; fs2[n] += v * v; }
        }
      }
    __syncthreads();

    for (int it = 0; it < 4; ++it) {
      int idx = it * 2048 + tid * 8;
      int r = idx >> 7, c = idx & 127;
      int row = row0 + r;
      if (row < nrows)
        *reinterpret_cast<uint4*>(hb + (long long)row * DD + c) =
            *reinterpret_cast<const uint4*>(&ldsH[r * LD + c]);
    }
    __syncthreads();
  }

  for (int off = 16; off < 64; off <<= 1)
    for (int n = 0; n < 2; ++n) {
      fs[n]  += __shfl_xor(fs[n], off);
      fs2[n] += __shfl_xor(fs2[n], off);
    }
  if (q == 0) {
    float* pb = partial + (long long)blockIdx.x * 256;
    for (int n = 0; n < 2; ++n) {
      int col = col0 + n * 16 + l16;
      pb[col]       = fs[n];
      pb[128 + col] = fs2[n];
    }
  }
}

__global__ __launch_bounds__(256) void k_stats(const float* __restrict__ partial,
                                               const float* __restrict__ gamma,
                                               const float* __restrict__ beta,
                                               float* __restrict__ scsh, int nrows) {
  __shared__ float red[256];
  int t = threadIdx.x;
  float s = 0.f;
  for (int b = 0; b < GRID; ++b) s += partial[(long long)b * 256 + t];
  red[t] = s;
  __syncthreads();
  if (t < 128) {
    float mean = red[t] / (float)nrows;
    float var  = fmaxf(red[128 + t] / (float)nrows - mean * mean, 0.f);
    float inv  = rsqrtf(var + 1e-5f);
    float sc   = gamma[t] * inv;
    scsh[t]       = sc;
    scsh[128 + t] = beta[t] - mean * sc;
  }
}

__global__ __launch_bounds__(256) void k_bn(const unsigned short* __restrict__ hbuf,
                                            float* __restrict__ out,
                                            const float* __restrict__ scsh,
                                            long long total8) {
  long long t = (long long)blockIdx.x * 256 + threadIdx.x;
  if (t >= total8) return;
  int c0 = (int)((t * 8) & 127);
  float4 sa = *reinterpret_cast<const float4*>(scsh + c0);
  float4 sb = *reinterpret_cast<const float4*>(scsh + c0 + 4);
  float4 ha = *reinterpret_cast<const float4*>(scsh + 128 + c0);
  float4 hb = *reinterpret_cast<const float4*>(scsh + 132 + c0);
  uint4 u = *reinterpret_cast<const uint4*>(hbuf + t * 8);
  float4 a, b;
  a.x = bf2f((unsigned short)(u.x & 0xFFFF)) * sa.x + ha.x;
  a.y = bf2f((unsigned short)(u.x >> 16))    * sa.y + ha.y;
  a.z = bf2f((unsigned short)(u.y & 0xFFFF)) * sa.z + ha.z;
  a.w = bf2f((unsigned short)(u.y >> 16))    * sa.w + ha.w;
  b.x = bf2f((unsigned short)(u.z & 0xFFFF)) * sb.x + hb.x;
  b.y = bf2f((unsigned short)(u.z >> 16))    * sb.y + hb.y;
  b.z = bf2f((unsigned short)(u.w & 0xFFFF)) * sb.z + hb.z;
  b.w = bf2f((unsigned short)(u.w >> 16))    * sb.w + hb.w;
  float* of = out + t * 8;
  *reinterpret_cast<float4*>(of)     = a;
  *reinterpret_cast<float4*>(of + 4) = b;
}

extern "C" void kernel_launch(void* const* d_in, const int* in_sizes, int n_in,
                              void* d_out, int out_size, void* d_ws, size_t ws_size,
                              hipStream_t stream) {
  const float* feat  = (const float*)d_in[0];
  const int*   eidx  = (const int*)d_in[1];
  const float* w1    = (const float*)d_in[2];
  const float* b1    = (const float*)d_in[3];
  const float* w2    = (const float*)d_in[4];
  const float* b2    = (const float*)d_in[5];
  const float* gamma = (const float*)d_in[6];
  const float* beta  = (const float*)d_in[7];
  float* out = (float*)d_out;

  const int nrows  = in_sizes[0] / DD;       // 100000
  const int ne     = in_sizes[1] / 2;        // 400000
  const int ntiles = (nrows + TM - 1) / TM;  // 1563

  // ws layout (4B words), hbuf last (16B-aligned by construction):
  int* base = (int*)d_ws;
  unsigned short* wbf1 = (unsigned short*)base;            // 16384 bf16
  unsigned short* wbf2 = (unsigned short*)(base + 8192);   // 16384 bf16
  float* scsh  = (float*)(base + 16384);                   // 256
  int*   ofs   = base + 16384 + 256;                       // nrows+1
  int*   cur   = ofs + (nrows + 1);
  int*   csr   = cur + nrows;
  int*   bsum  = csr + ne;                                 // GRID
  int*   bofs  = bsum + GRID;                              // GRID
  float* partial = (float*)(bofs + GRID);                  // GRID*256 (1 MB)
  int*   cnt   = (int*)(partial + (size_t)GRID * 256);     // nrows
  long long w_off = (long long)(cnt + nrows - base);
  w_off = (w_off + 3) & ~3LL;                              // 16B align
  unsigned short* hbuf = (unsigned short*)(base + w_off);  // nrows*DD bf16 (25.6 MB)

  int nrows_a = nrows, ne_a = ne, ntiles_a = ntiles;
  void* args[] = {
    (void*)&feat, (void*)&eidx, (void*)&w1, (void*)&b1, (void*)&w2, (void*)&b2,
    (void*)&gamma, (void*)&beta, (void*)&out,
    (void*)&wbf1, (void*)&wbf2,
    (void*)&cnt, (void*)&ofs, (void*)&cur, (void*)&csr, (void*)&bsum, (void*)&bofs,
    (void*)&partial, (void*)&scsh, (void*)&hbuf,
    (void*)&nrows_a, (void*)&ne_a, (void*)&ntiles_a
  };
  hipError_t err = hipLaunchCooperativeKernel((const void*)k_fused, dim3(GRID), dim3(BLK),
                                              args, 0, stream);
  if (err == hipSuccess) return;

  // Fallback: round-3 multi-kernel path.
  hipMemsetAsync(cnt, 0, (size_t)nrows * sizeof(int), stream);
  const long long total8 = (long long)nrows * DD / 8;
  const int agg_blocks = (nrows * 16 + 255) / 256;
  k_prep <<<(DD * DD + 255) / 256,        256, 0, stream>>>(w1, w2, wbf1, wbf2);
  k_hist <<<(ne + 255) / 256,             256, 0, stream>>>(eidx, cnt, ne);
  k_scan1<<<SB,                           256, 0, stream>>>(cnt, bsum, nrows);
  k_scan2<<<1,                             SB, 0, stream>>>(bsum, bofs, ofs, nrows);
  k_scan3<<<SB,                           256, 0, stream>>>(cnt, bofs, ofs, cur, nrows);
  k_fill <<<(ne + 255) / 256,             256, 0, stream>>>(eidx, cur, csr, ne);
  k_agg  <<<agg_blocks,                   256, 0, stream>>>(feat, ofs, csr, hbuf, nrows);
  k_mlp  <<<GRID,                         256, 0, stream>>>(hbuf, wbf1, b1, wbf2, b2,
                                                            partial, nrows, ntiles);
  k_stats<<<1,                            256, 0, stream>>>(partial, gamma, beta, scsh, nrows);
  k_bn   <<<(int)((total8 + 255) / 256),  256, 0, stream>>>(hbuf, out, scsh, total8);
}

// Round 5
// 376.807 us; speedup vs baseline: 3.2728x; 3.2728x over previous
//
#include <hip/hip_runtime.h>
#include <hip/hip_bf16.h>

#define DD 128
#define TM 64
#define LD 136        // padded LDS row stride (bf16 elems)
#define SB 128        // scan blocks
#define GRID_MLP 1024 // 4 blocks/CU persistent

typedef short bf16x8 __attribute__((ext_vector_type(8)));
typedef float f32x4  __attribute__((ext_vector_type(4)));

__device__ __forceinline__ unsigned short f2bf(float f) {
  unsigned int u = __float_as_uint(f);
  u += 0x7FFFu + ((u >> 16) & 1u);   // RNE
  return (unsigned short)(u >> 16);
}
__device__ __forceinline__ unsigned int pack2(float lo, float hi) {
  return (unsigned int)f2bf(lo) | ((unsigned int)f2bf(hi) << 16);
}
__device__ __forceinline__ float bf2f(unsigned short u) {
  union { unsigned int i; float f; } x; x.i = ((unsigned int)u) << 16; return x.f;
}

// init: zero cnt + ticket, convert weights fp32->bf16. One dispatch.
__global__ __launch_bounds__(256) void k_init(const float* __restrict__ w1,
                                              const float* __restrict__ w2,
                                              unsigned short* __restrict__ wbf1,
                                              unsigned short* __restrict__ wbf2,
                                              int* __restrict__ cnt,
                                              int* __restrict__ done, int nrows) {
  int i = blockIdx.x * 256 + threadIdx.x;
  if (i < nrows) cnt[i] = 0;
  if (i < DD * DD) { wbf1[i] = f2bf(w1[i]); wbf2[i] = f2bf(w2[i]); }
  if (i == 0) *done = 0;
}

// cnt[dst]++ per edge (int atomics, L2-resident)
__global__ __launch_bounds__(256) void k_hist(const int* __restrict__ ei, int* __restrict__ cnt,
                                              int ne) {
  int e = blockIdx.x * 256 + threadIdx.x;
  if (e < ne) atomicAdd(&cnt[ei[ne + e]], 1);
}

// scan stage 1: per-block chunk sums
__global__ __launch_bounds__(256) void k_scan1(const int* __restrict__ cnt,
                                               int* __restrict__ bsum, int n) {
  __shared__ int red[256];
  int b = blockIdx.x, t = threadIdx.x;
  int chunk = (n + SB - 1) / SB;
  int lo = b * chunk, hi = min(n, lo + chunk);
  int s = 0;
  for (int i = lo + t; i < hi; i += 256) s += cnt[i];
  red[t] = s;
  __syncthreads();
  for (int off = 128; off; off >>= 1) {
    if (t < off) red[t] += red[t + off];
    __syncthreads();
  }
  if (t == 0) bsum[b] = red[0];
}

// scan stage 2: each block redundantly scans bsum[SB] in LDS (kills k_scan2),
// then exclusive-scans its chunk -> ofs, cur.
__global__ __launch_bounds__(256) void k_scan3(const int* __restrict__ cnt,
                                               const int* __restrict__ bsum,
                                               int* __restrict__ ofs, int* __restrict__ cur,
                                               int n) {
  __shared__ int red[256];
  __shared__ int sbs[SB];
  int b = blockIdx.x, t = threadIdx.x;

  // redundant exclusive scan of bsum[0..SB) in LDS
  int ov = (t < SB) ? bsum[t] : 0;
  if (t < SB) sbs[t] = ov;
  __syncthreads();
  for (int off = 1; off < SB; off <<= 1) {
    int v = (t < SB && t >= off) ? sbs[t - off] : 0;
    __syncthreads();
    if (t < SB) sbs[t] += v;
    __syncthreads();
  }
  if (t < SB) sbs[t] -= ov;   // exclusive
  __syncthreads();
  int base = sbs[b];
  if (b == SB - 1 && t == SB - 1) ofs[n] = sbs[t] + ov;  // total

  int chunk  = (n + SB - 1) / SB;
  int tchunk = (chunk + 255) / 256;
  int blo = b * chunk, bhi = min(n, blo + chunk);
  int lo = blo + t * tchunk, hi = min(bhi, lo + tchunk);
  int s = 0;
  for (int i = lo; i < hi; ++i) s += cnt[i];
  int mine = s;
  red[t] = s;
  __syncthreads();
  for (int off = 1; off < 256; off <<= 1) {
    int v = (t >= off) ? red[t - off] : 0;
    __syncthreads();
    red[t] += v;
    __syncthreads();
  }
  int run = base + red[t] - mine;
  for (int i = lo; i < hi; ++i) {
    int c = cnt[i];
    ofs[i] = run; cur[i] = run;
    run += c;
  }
}

// csr[pos] = src, pos = cur[dst]++
__global__ __launch_bounds__(256) void k_fill(const int* __restrict__ ei, int* __restrict__ cur,
                                              int* __restrict__ csr, int ne) {
  int e = blockIdx.x * 256 + threadIdx.x;
  if (e >= ne) return;
  int pos = atomicAdd(&cur[ei[ne + e]], 1);
  csr[pos] = ei[e];
}

// Dedicated high-occupancy gather: h = feat[row] + sum(neighbors), fp32 accum,
// RNE-pack to bf16 into agg (== hbuf). Demand-bandwidth-bound (~6.7 TB/s mixed).
__global__ __launch_bounds__(256) void k_agg(
    const float* __restrict__ feat, const int* __restrict__ ofs, const int* __restrict__ csr,
    unsigned short* __restrict__ agg, int nrows)
{
  int t = blockIdx.x * 256 + threadIdx.x;   // 16 threads per row, 8 cols each
  int row = t >> 4;
  if (row >= nrows) return;
  int c = (t & 15) * 8;
  const float* fr = feat + (long long)row * DD + c;
  float4 a0 = *reinterpret_cast<const float4*>(fr);
  float4 b0 = *reinterpret_cast<const float4*>(fr + 4);
  float4 a1 = make_float4(0.f, 0.f, 0.f, 0.f);
  float4 b1 = make_float4(0.f, 0.f, 0.f, 0.f);
  int o0 = ofs[row], o1 = ofs[row + 1];
  int j = o0;
  for (; j + 2 <= o1; j += 2) {
    const float* f0 = feat + (long long)csr[j]     * DD + c;
    const float* f1 = feat + (long long)csr[j + 1] * DD + c;
    float4 x0 = *reinterpret_cast<const float4*>(f0);
    float4 y0 = *reinterpret_cast<const float4*>(f0 + 4);
    float4 x1 = *reinterpret_cast<const float4*>(f1);
    float4 y1 = *reinterpret_cast<const float4*>(f1 + 4);
    a0.x += x0.x; a0.y += x0.y; a0.z += x0.z; a0.w += x0.w;
    b0.x += y0.x; b0.y += y0.y; b0.z += y0.z; b0.w += y0.w;
    a1.x += x1.x; a1.y += x1.y; a1.z += x1.z; a1.w += x1.w;
    b1.x += y1.x; b1.y += y1.y; b1.z += y1.z; b1.w += y1.w;
  }
  if (j < o1) {
    const float* f0 = feat + (long long)csr[j] * DD + c;
    float4 x0 = *reinterpret_cast<const float4*>(f0);
    float4 y0 = *reinterpret_cast<const float4*>(f0 + 4);
    a0.x += x0.x; a0.y += x0.y; a0.z += x0.z; a0.w += x0.w;
    b0.x += y0.x; b0.y += y0.y; b0.z += y0.z; b0.w += y0.w;
  }
  a0.x += a1.x; a0.y += a1.y; a0.z += a1.z; a0.w += a1.w;
  b0.x += b1.x; b0.y += b1.y; b0.z += b1.z; b0.w += b1.w;
  uint4 u;
  u.x = pack2(a0.x, a0.y); u.y = pack2(a0.z, a0.w);
  u.z = pack2(b0.x, b0.y); u.w = pack2(b0.z, b0.w);
  *reinterpret_cast<uint4*>(agg + (long long)row * DD + c) = u;
}

// Persistent fused MLP: per 64-row tile — stream bf16 tile from hb, 2-layer MLP
// via bf16 MFMA, in-place write-back. BN stats: register-accumulated, one
// non-atomic store per block; LAST block (ticket) reduces partial -> scsh.
__global__ __launch_bounds__(256) void k_mlp(
    unsigned short* hb,
    const unsigned short* __restrict__ wbf1, const float* __restrict__ b1,
    const unsigned short* __restrict__ wbf2, const float* __restrict__ b2,
    float* __restrict__ partial, int* __restrict__ done,
    const float* __restrict__ gamma, const float* __restrict__ beta,
    float* __restrict__ scsh, int nrows, int ntiles)
{
  __shared__ unsigned short ldsH[TM * LD];
  __shared__ unsigned short ldsH2[TM * LD];
  const int tid  = threadIdx.x;
  const int wave = tid >> 6, lane = tid & 63;
  const int q = lane >> 4, l16 = lane & 15;
  const int col0 = wave * 32;

  bf16x8 bw1[2][4], bw2[2][4];
  float bias1[2], bias2[2];
  for (int n = 0; n < 2; ++n) {
    int jc = col0 + n * 16 + l16;
    bias1[n] = b1[jc];
    bias2[n] = b2[jc];
    for (int kk = 0; kk < 4; ++kk) {
      bw1[n][kk] = *reinterpret_cast<const bf16x8*>(wbf1 + jc * DD + kk * 32 + q * 8);
      bw2[n][kk] = *reinterpret_cast<const bf16x8*>(wbf2 + jc * DD + kk * 32 + q * 8);
    }
  }

  float fs[2] = {0.f, 0.f}, fs2[2] = {0.f, 0.f};

  for (int tile = blockIdx.x; tile < ntiles; tile += GRID_MLP) {
    const int row0 = tile * TM;

    for (int it = 0; it < 4; ++it) {
      int idx = it * 2048 + tid * 8;
      int r = idx >> 7, c = idx & 127;
      int row = row0 + r;
      uint4 u = make_uint4(0u, 0u, 0u, 0u);
      if (row < nrows)
        u = *reinterpret_cast<const uint4*>(hb + (long long)row * DD + c);
      *reinterpret_cast<uint4*>(&ldsH[r * LD + c]) = u;
    }
    __syncthreads();

    f32x4 acc[4][2];
    const f32x4 zero = {0.f, 0.f, 0.f, 0.f};
    for (int m = 0; m < 4; ++m) for (int n = 0; n < 2; ++n) acc[m][n] = zero;

    for (int kk = 0; kk < 4; ++kk) {
      bf16x8 aF[4];
      for (int m = 0; m < 4; ++m)
        aF[m] = *reinterpret_cast<const bf16x8*>(&ldsH[(m * 16 + l16) * LD + kk * 32 + q * 8]);
      for (int m = 0; m < 4; ++m)
        for (int n = 0; n < 2; ++n)
          acc[m][n] = __builtin_amdgcn_mfma_f32_16x16x32_bf16(aF[m], bw1[n][kk], acc[m][n], 0, 0, 0);
    }

    for (int m = 0; m < 4; ++m)
      for (int n = 0; n < 2; ++n)
        for (int r = 0; r < 4; ++r) {
          float v = fmaxf(acc[m][n][r] + bias1[n], 0.f);
          ldsH2[(m * 16 + q * 4 + r) * LD + (col0 + n * 16 + l16)] = f2bf(v);
        }
    __syncthreads();

    for (int m = 0; m < 4; ++m) for (int n = 0; n < 2; ++n) acc[m][n] = zero;

    for (int kk = 0; kk < 4; ++kk) {
      bf16x8 aF[4];
      for (int m = 0; m < 4; ++m)
        aF[m] = *reinterpret_cast<const bf16x8*>(&ldsH2[(m * 16 + l16) * LD + kk * 32 + q * 8]);
      for (int m = 0; m < 4; ++m)
        for (int n = 0; n < 2; ++n)
          acc[m][n] = __builtin_amdgcn_mfma_f32_16x16x32_bf16(aF[m], bw2[n][kk], acc[m][n], 0, 0, 0);
    }

    for (int m = 0; m < 4; ++m)
      for (int n = 0; n < 2; ++n) {
        int col = col0 + n * 16 + l16;
        for (int r = 0; r < 4; ++r) {
          int rl = m * 16 + q * 4 + r;
          float v = fmaxf(acc[m][n][r] + bias2[n], 0.f);
          ldsH[rl * LD + col] = f2bf(v);
          if (row0 + rl < nrows) { fs[n] += v; fs2[n] += v * v; }
        }
      }
    __syncthreads();

    for (int it = 0; it < 4; ++it) {
      int idx = it * 2048 + tid * 8;
      int r = idx >> 7, c = idx & 127;
      int row = row0 + r;
      if (row < nrows)
        *reinterpret_cast<uint4*>(hb + (long long)row * DD + c) =
            *reinterpret_cast<const uint4*>(&ldsH[r * LD + c]);
    }
    __syncthreads();
  }

  // per-block partial store (non-atomic)
  for (int off = 16; off < 64; off <<= 1)
    for (int n = 0; n < 2; ++n) {
      fs[n]  += __shfl_xor(fs[n], off);
      fs2[n] += __shfl_xor(fs2[n], off);
    }
  if (q == 0) {
    float* pb = partial + (long long)blockIdx.x * 256;
    for (int n = 0; n < 2; ++n) {
      int col = col0 + n * 16 + l16;
      pb[col]       = fs[n];
      pb[128 + col] = fs2[n];
    }
  }

  // last-block ticket: reduce partial -> scsh (replaces k_stats dispatch)
  __threadfence();
  __shared__ int isLast;
  if (tid == 0) isLast = (atomicAdd(done, 1) == GRID_MLP - 1) ? 1 : 0;
  __syncthreads();
  if (isLast) {
    __threadfence();
    float s = 0.f;
    const float* pc = partial + tid;
    #pragma unroll 4
    for (int r = 0; r < GRID_MLP; ++r) s += pc[(long long)r * 256];
    float* fred = reinterpret_cast<float*>(ldsH);
    fred[tid] = s;
    __syncthreads();
    if (tid < 128) {
      float mean = fred[tid] / (float)nrows;
      float var  = fmaxf(fred[128 + tid] / (float)nrows - mean * mean, 0.f);
      float inv  = rsqrtf(var + 1e-5f);
      float sc   = gamma[tid] * inv;
      scsh[tid]       = sc;
      scsh[128 + tid] = beta[tid] - mean * sc;
    }
  }
}

// BN apply: read bf16 hbuf (L3-warm), write fp32 out. One thread per 8 elems.
__global__ __launch_bounds__(256) void k_bn(const unsigned short* __restrict__ hbuf,
                                            float* __restrict__ out,
                                            const float* __restrict__ scsh,
                                            long long total8) {
  long long t = (long long)blockIdx.x * 256 + threadIdx.x;
  if (t >= total8) return;
  int c0 = (int)((t * 8) & 127);
  float4 sa = *reinterpret_cast<const float4*>(scsh + c0);
  float4 sb = *reinterpret_cast<const float4*>(scsh + c0 + 4);
  float4 ha = *reinterpret_cast<const float4*>(scsh + 128 + c0);
  float4 hb = *reinterpret_cast<const float4*>(scsh + 132 + c0);
  uint4 u = *reinterpret_cast<const uint4*>(hbuf + t * 8);
  float4 a, b;
  a.x = bf2f((unsigned short)(u.x & 0xFFFF)) * sa.x + ha.x;
  a.y = bf2f((unsigned short)(u.x >> 16))    * sa.y + ha.y;
  a.z = bf2f((unsigned short)(u.y & 0xFFFF)) * sa.z + ha.z;
  a.w = bf2f((unsigned short)(u.y >> 16))    * sa.w + ha.w;
  b.x = bf2f((unsigned short)(u.z & 0xFFFF)) * sb.x + hb.x;
  b.y = bf2f((unsigned short)(u.z >> 16))    * sb.y + hb.y;
  b.z = bf2f((unsigned short)(u.w & 0xFFFF)) * sb.z + hb.z;
  b.w = bf2f((unsigned short)(u.w >> 16))    * sb.w + hb.w;
  float* of = out + t * 8;
  *reinterpret_cast<float4*>(of)     = a;
  *reinterpret_cast<float4*>(of + 4) = b;
}

extern "C" void kernel_launch(void* const* d_in, const int* in_sizes, int n_in,
                              void* d_out, int out_size, void* d_ws, size_t ws_size,
                              hipStream_t stream) {
  const float* feat  = (const float*)d_in[0];
  const int*   eidx  = (const int*)d_in[1];
  const float* w1    = (const float*)d_in[2];
  const float* b1    = (const float*)d_in[3];
  const float* w2    = (const float*)d_in[4];
  const float* b2    = (const float*)d_in[5];
  const float* gamma = (const float*)d_in[6];
  const float* beta  = (const float*)d_in[7];
  float* out = (float*)d_out;

  const int nrows  = in_sizes[0] / DD;       // 100000
  const int ne     = in_sizes[1] / 2;        // 400000
  const int ntiles = (nrows + TM - 1) / TM;  // 1563

  // ws layout (4B words), hbuf last (16B-aligned by construction):
  int* base = (int*)d_ws;
  unsigned short* wbf1 = (unsigned short*)base;            // 16384 bf16
  unsigned short* wbf2 = (unsigned short*)(base + 8192);   // 16384 bf16
  float* scsh  = (float*)(base + 16384);                   // 256
  int*   ofs   = base + 16384 + 256;                       // nrows+1
  int*   cur   = ofs + (nrows + 1);
  int*   csr   = cur + nrows;
  int*   bsum  = csr + ne;                                 // SB
  int*   done  = bsum + SB;                                // 4 (1 used)
  float* partial = (float*)(done + 4);                     // GRID_MLP*256 (1 MB)
  int*   cnt   = (int*)(partial + (size_t)GRID_MLP * 256); // nrows
  long long w_off = (long long)(cnt + nrows - base);
  w_off = (w_off + 3) & ~3LL;                              // 16B align
  unsigned short* hbuf = (unsigned short*)(base + w_off);  // nrows*DD bf16 (25.6 MB)

  const long long total8 = (long long)nrows * DD / 8;      // 1.6M
  const int agg_blocks  = (nrows * 16 + 255) / 256;        // 6250
  const int init_blocks = (nrows + 255) / 256;             // 391

  k_init <<<init_blocks,                  256, 0, stream>>>(w1, w2, wbf1, wbf2, cnt, done, nrows);
  k_hist <<<(ne + 255) / 256,             256, 0, stream>>>(eidx, cnt, ne);
  k_scan1<<<SB,                           256, 0, stream>>>(cnt, bsum, nrows);
  k_scan3<<<SB,                           256, 0, stream>>>(cnt, bsum, ofs, cur, nrows);
  k_fill <<<(ne + 255) / 256,             256, 0, stream>>>(eidx, cur, csr, ne);
  k_agg  <<<agg_blocks,                   256, 0, stream>>>(feat, ofs, csr, hbuf, nrows);
  k_mlp  <<<GRID_MLP,                     256, 0, stream>>>(hbuf, wbf1, b1, wbf2, b2,
                                                            partial, done, gamma, beta, scsh,
                                                            nrows, ntiles);
  k_bn   <<<(int)((total8 + 255) / 256),  256, 0, stream>>>(hbuf, out, scsh, total8);
}

// Round 6
// 246.264 us; speedup vs baseline: 5.0077x; 1.5301x over previous
//
#include <hip/hip_runtime.h>
#include <hip/hip_bf16.h>

#define DD 128
#define TM 64
#define LD 136        // padded LDS row stride (bf16 elems)
#define SB 128        // scan blocks
#define GRID_MLP 1024 // 4 blocks/CU persistent

typedef short bf16x8 __attribute__((ext_vector_type(8)));
typedef float f32x4  __attribute__((ext_vector_type(4)));

__device__ __forceinline__ unsigned short f2bf(float f) {
  unsigned int u = __float_as_uint(f);
  u += 0x7FFFu + ((u >> 16) & 1u);   // RNE
  return (unsigned short)(u >> 16);
}
__device__ __forceinline__ unsigned int pack2(float lo, float hi) {
  return (unsigned int)f2bf(lo) | ((unsigned int)f2bf(hi) << 16);
}
__device__ __forceinline__ float bf2f(unsigned short u) {
  union { unsigned int i; float f; } x; x.i = ((unsigned int)u) << 16; return x.f;
}

// init: zero cnt, convert weights fp32->bf16. One dispatch (replaces memset+prep).
__global__ __launch_bounds__(256) void k_init(const float* __restrict__ w1,
                                              const float* __restrict__ w2,
                                              unsigned short* __restrict__ wbf1,
                                              unsigned short* __restrict__ wbf2,
                                              int* __restrict__ cnt, int nrows) {
  int i = blockIdx.x * 256 + threadIdx.x;
  if (i < nrows) cnt[i] = 0;
  if (i < DD * DD) { wbf1[i] = f2bf(w1[i]); wbf2[i] = f2bf(w2[i]); }
}

// cnt[dst]++ per edge (int atomics, L2-resident)
__global__ __launch_bounds__(256) void k_hist(const int* __restrict__ ei, int* __restrict__ cnt,
                                              int ne) {
  int e = blockIdx.x * 256 + threadIdx.x;
  if (e < ne) atomicAdd(&cnt[ei[ne + e]], 1);
}

// scan stage 1: per-block chunk sums
__global__ __launch_bounds__(256) void k_scan1(const int* __restrict__ cnt,
                                               int* __restrict__ bsum, int n) {
  __shared__ int red[256];
  int b = blockIdx.x, t = threadIdx.x;
  int chunk = (n + SB - 1) / SB;
  int lo = b * chunk, hi = min(n, lo + chunk);
  int s = 0;
  for (int i = lo + t; i < hi; i += 256) s += cnt[i];
  red[t] = s;
  __syncthreads();
  for (int off = 128; off; off >>= 1) {
    if (t < off) red[t] += red[t + off];
    __syncthreads();
  }
  if (t == 0) bsum[b] = red[0];
}

// scan stage 2: each block redundantly scans bsum[SB] in LDS (folds old k_scan2),
// then exclusive-scans its chunk -> ofs, cur.
__global__ __launch_bounds__(256) void k_scan3(const int* __restrict__ cnt,
                                               const int* __restrict__ bsum,
                                               int* __restrict__ ofs, int* __restrict__ cur,
                                               int n) {
  __shared__ int red[256];
  __shared__ int sbs[SB];
  int b = blockIdx.x, t = threadIdx.x;

  // redundant exclusive scan of bsum[0..SB) in LDS
  int ov = (t < SB) ? bsum[t] : 0;
  if (t < SB) sbs[t] = ov;
  __syncthreads();
  for (int off = 1; off < SB; off <<= 1) {
    int v = (t < SB && t >= off) ? sbs[t - off] : 0;
    __syncthreads();
    if (t < SB) sbs[t] += v;
    __syncthreads();
  }
  if (t < SB) sbs[t] -= ov;   // exclusive
  __syncthreads();
  int base = sbs[b];
  if (b == SB - 1 && t == SB - 1) ofs[n] = sbs[t] + ov;  // total

  int chunk  = (n + SB - 1) / SB;
  int tchunk = (chunk + 255) / 256;
  int blo = b * chunk, bhi = min(n, blo + chunk);
  int lo = blo + t * tchunk, hi = min(bhi, lo + tchunk);
  int s = 0;
  for (int i = lo; i < hi; ++i) s += cnt[i];
  int mine = s;
  red[t] = s;
  __syncthreads();
  for (int off = 1; off < 256; off <<= 1) {
    int v = (t >= off) ? red[t - off] : 0;
    __syncthreads();
    red[t] += v;
    __syncthreads();
  }
  int run = base + red[t] - mine;
  for (int i = lo; i < hi; ++i) {
    int c = cnt[i];
    ofs[i] = run; cur[i] = run;
    run += c;
  }
}

// csr[pos] = src, pos = cur[dst]++
__global__ __launch_bounds__(256) void k_fill(const int* __restrict__ ei, int* __restrict__ cur,
                                              int* __restrict__ csr, int ne) {
  int e = blockIdx.x * 256 + threadIdx.x;
  if (e >= ne) return;
  int pos = atomicAdd(&cur[ei[ne + e]], 1);
  csr[pos] = ei[e];
}

// Dedicated high-occupancy gather: h = feat[row] + sum(neighbors), fp32 accum,
// RNE-pack to bf16 into agg (== hbuf). Demand-bandwidth-bound (~6.7 TB/s mixed).
__global__ __launch_bounds__(256) void k_agg(
    const float* __restrict__ feat, const int* __restrict__ ofs, const int* __restrict__ csr,
    unsigned short* __restrict__ agg, int nrows)
{
  int t = blockIdx.x * 256 + threadIdx.x;   // 16 threads per row, 8 cols each
  int row = t >> 4;
  if (row >= nrows) return;
  int c = (t & 15) * 8;
  const float* fr = feat + (long long)row * DD + c;
  float4 a0 = *reinterpret_cast<const float4*>(fr);
  float4 b0 = *reinterpret_cast<const float4*>(fr + 4);
  float4 a1 = make_float4(0.f, 0.f, 0.f, 0.f);
  float4 b1 = make_float4(0.f, 0.f, 0.f, 0.f);
  int o0 = ofs[row], o1 = ofs[row + 1];
  int j = o0;
  for (; j + 2 <= o1; j += 2) {
    const float* f0 = feat + (long long)csr[j]     * DD + c;
    const float* f1 = feat + (long long)csr[j + 1] * DD + c;
    float4 x0 = *reinterpret_cast<const float4*>(f0);
    float4 y0 = *reinterpret_cast<const float4*>(f0 + 4);
    float4 x1 = *reinterpret_cast<const float4*>(f1);
    float4 y1 = *reinterpret_cast<const float4*>(f1 + 4);
    a0.x += x0.x; a0.y += x0.y; a0.z += x0.z; a0.w += x0.w;
    b0.x += y0.x; b0.y += y0.y; b0.z += y0.z; b0.w += y0.w;
    a1.x += x1.x; a1.y += x1.y; a1.z += x1.z; a1.w += x1.w;
    b1.x += y1.x; b1.y += y1.y; b1.z += y1.z; b1.w += y1.w;
  }
  if (j < o1) {
    const float* f0 = feat + (long long)csr[j] * DD + c;
    float4 x0 = *reinterpret_cast<const float4*>(f0);
    float4 y0 = *reinterpret_cast<const float4*>(f0 + 4);
    a0.x += x0.x; a0.y += x0.y; a0.z += x0.z; a0.w += x0.w;
    b0.x += y0.x; b0.y += y0.y; b0.z += y0.z; b0.w += y0.w;
  }
  a0.x += a1.x; a0.y += a1.y; a0.z += a1.z; a0.w += a1.w;
  b0.x += b1.x; b0.y += b1.y; b0.z += b1.z; b0.w += b1.w;
  uint4 u;
  u.x = pack2(a0.x, a0.y); u.y = pack2(a0.z, a0.w);
  u.z = pack2(b0.x, b0.y); u.w = pack2(b0.z, b0.w);
  *reinterpret_cast<uint4*>(agg + (long long)row * DD + c) = u;
}

// Persistent fused MLP: per 64-row tile — stream bf16 tile from hb, 2-layer MLP
// via bf16 MFMA, in-place write-back. BN stats: register-accumulated, one
// non-atomic store per block. NO device-scope sync inside (kernel boundary is
// the cheap global barrier on multi-XCD gfx950 — R4/R5 lesson).
__global__ __launch_bounds__(256) void k_mlp(
    unsigned short* hb,
    const unsigned short* __restrict__ wbf1, const float* __restrict__ b1,
    const unsigned short* __restrict__ wbf2, const float* __restrict__ b2,
    float* __restrict__ partial, int nrows, int ntiles)
{
  __shared__ unsigned short ldsH[TM * LD];
  __shared__ unsigned short ldsH2[TM * LD];
  const int tid  = threadIdx.x;
  const int wave = tid >> 6, lane = tid & 63;
  const int q = lane >> 4, l16 = lane & 15;
  const int col0 = wave * 32;

  bf16x8 bw1[2][4], bw2[2][4];
  float bias1[2], bias2[2];
  for (int n = 0; n < 2; ++n) {
    int jc = col0 + n * 16 + l16;
    bias1[n] = b1[jc];
    bias2[n] = b2[jc];
    for (int kk = 0; kk < 4; ++kk) {
      bw1[n][kk] = *reinterpret_cast<const bf16x8*>(wbf1 + jc * DD + kk * 32 + q * 8);
      bw2[n][kk] = *reinterpret_cast<const bf16x8*>(wbf2 + jc * DD + kk * 32 + q * 8);
    }
  }

  float fs[2] = {0.f, 0.f}, fs2[2] = {0.f, 0.f};

  for (int tile = blockIdx.x; tile < ntiles; tile += GRID_MLP) {
    const int row0 = tile * TM;

    for (int it = 0; it < 4; ++it) {
      int idx = it * 2048 + tid * 8;
      int r = idx >> 7, c = idx & 127;
      int row = row0 + r;
      uint4 u = make_uint4(0u, 0u, 0u, 0u);
      if (row < nrows)
        u = *reinterpret_cast<const uint4*>(hb + (long long)row * DD + c);
      *reinterpret_cast<uint4*>(&ldsH[r * LD + c]) = u;
    }
    __syncthreads();

    f32x4 acc[4][2];
    const f32x4 zero = {0.f, 0.f, 0.f, 0.f};
    for (int m = 0; m < 4; ++m) for (int n = 0; n < 2; ++n) acc[m][n] = zero;

    for (int kk = 0; kk < 4; ++kk) {
      bf16x8 aF[4];
      for (int m = 0; m < 4; ++m)
        aF[m] = *reinterpret_cast<const bf16x8*>(&ldsH[(m * 16 + l16) * LD + kk * 32 + q * 8]);
      for (int m = 0; m < 4; ++m)
        for (int n = 0; n < 2; ++n)
          acc[m][n] = __builtin_amdgcn_mfma_f32_16x16x32_bf16(aF[m], bw1[n][kk], acc[m][n], 0, 0, 0);
    }

    for (int m = 0; m < 4; ++m)
      for (int n = 0; n < 2; ++n)
        for (int r = 0; r < 4; ++r) {
          float v = fmaxf(acc[m][n][r] + bias1[n], 0.f);
          ldsH2[(m * 16 + q * 4 + r) * LD + (col0 + n * 16 + l16)] = f2bf(v);
        }
    __syncthreads();

    for (int m = 0; m < 4; ++m) for (int n = 0; n < 2; ++n) acc[m][n] = zero;

    for (int kk = 0; kk < 4; ++kk) {
      bf16x8 aF[4];
      for (int m = 0; m < 4; ++m)
        aF[m] = *reinterpret_cast<const bf16x8*>(&ldsH2[(m * 16 + l16) * LD + kk * 32 + q * 8]);
      for (int m = 0; m < 4; ++m)
        for (int n = 0; n < 2; ++n)
          acc[m][n] = __builtin_amdgcn_mfma_f32_16x16x32_bf16(aF[m], bw2[n][kk], acc[m][n], 0, 0, 0);
    }

    for (int m = 0; m < 4; ++m)
      for (int n = 0; n < 2; ++n) {
        int col = col0 + n * 16 + l16;
        for (int r = 0; r < 4; ++r) {
          int rl = m * 16 + q * 4 + r;
          float v = fmaxf(acc[m][n][r] + bias2[n], 0.f);
          ldsH[rl * LD + col] = f2bf(v);
          if (row0 + rl < nrows) { fs[n] += v; fs2[n] += v * v; }
        }
      }
    __syncthreads();

    for (int it = 0; it < 4; ++it) {
      int idx = it * 2048 + tid * 8;
      int r = idx >> 7, c = idx & 127;
      int row = row0 + r;
      if (row < nrows)
        *reinterpret_cast<uint4*>(hb + (long long)row * DD + c) =
            *reinterpret_cast<const uint4*>(&ldsH[r * LD + c]);
    }
    __syncthreads();
  }

  // per-block partial store (non-atomic)
  for (int off = 16; off < 64; off <<= 1)
    for (int n = 0; n < 2; ++n) {
      fs[n]  += __shfl_xor(fs[n], off);
      fs2[n] += __shfl_xor(fs2[n], off);
    }
  if (q == 0) {
    float* pb = partial + (long long)blockIdx.x * 256;
    for (int n = 0; n < 2; ++n) {
      int col = col0 + n * 16 + l16;
      pb[col]       = fs[n];
      pb[128 + col] = fs2[n];
    }
  }
}

// Reduce per-block partials -> scale/shift (tiny; after-boundary data is clean)
__global__ __launch_bounds__(256) void k_stats(const float* __restrict__ partial,
                                               const float* __restrict__ gamma,
                                               const float* __restrict__ beta,
                                               float* __restrict__ scsh, int nrows) {
  __shared__ float red[256];
  int t = threadIdx.x;
  float s = 0.f;
  for (int b = 0; b < GRID_MLP; ++b) s += partial[(long long)b * 256 + t];
  red[t] = s;
  __syncthreads();
  if (t < 128) {
    float mean = red[t] / (float)nrows;
    float var  = fmaxf(red[128 + t] / (float)nrows - mean * mean, 0.f);
    float inv  = rsqrtf(var + 1e-5f);
    float sc   = gamma[t] * inv;
    scsh[t]       = sc;
    scsh[128 + t] = beta[t] - mean * sc;
  }
}

// BN apply: read bf16 hbuf (L3-warm), write fp32 out. One thread per 8 elems.
__global__ __launch_bounds__(256) void k_bn(const unsigned short* __restrict__ hbuf,
                                            float* __restrict__ out,
                                            const float* __restrict__ scsh,
                                            long long total8) {
  long long t = (long long)blockIdx.x * 256 + threadIdx.x;
  if (t >= total8) return;
  int c0 = (int)((t * 8) & 127);
  float4 sa = *reinterpret_cast<const float4*>(scsh + c0);
  float4 sb = *reinterpret_cast<const float4*>(scsh + c0 + 4);
  float4 ha = *reinterpret_cast<const float4*>(scsh + 128 + c0);
  float4 hb = *reinterpret_cast<const float4*>(scsh + 132 + c0);
  uint4 u = *reinterpret_cast<const uint4*>(hbuf + t * 8);
  float4 a, b;
  a.x = bf2f((unsigned short)(u.x & 0xFFFF)) * sa.x + ha.x;
  a.y = bf2f((unsigned short)(u.x >> 16))    * sa.y + ha.y;
  a.z = bf2f((unsigned short)(u.y & 0xFFFF)) * sa.z + ha.z;
  a.w = bf2f((unsigned short)(u.y >> 16))    * sa.w + ha.w;
  b.x = bf2f((unsigned short)(u.z & 0xFFFF)) * sb.x + hb.x;
  b.y = bf2f((unsigned short)(u.z >> 16))    * sb.y + hb.y;
  b.z = bf2f((unsigned short)(u.w & 0xFFFF)) * sb.z + hb.z;
  b.w = bf2f((unsigned short)(u.w >> 16))    * sb.w + hb.w;
  float* of = out + t * 8;
  *reinterpret_cast<float4*>(of)     = a;
  *reinterpret_cast<float4*>(of + 4) = b;
}

extern "C" void kernel_launch(void* const* d_in, const int* in_sizes, int n_in,
                              void* d_out, int out_size, void* d_ws, size_t ws_size,
                              hipStream_t stream) {
  const float* feat  = (const float*)d_in[0];
  const int*   eidx  = (const int*)d_in[1];
  const float* w1    = (const float*)d_in[2];
  const float* b1    = (const float*)d_in[3];
  const float* w2    = (const float*)d_in[4];
  const float* b2    = (const float*)d_in[5];
  const float* gamma = (const float*)d_in[6];
  const float* beta  = (const float*)d_in[7];
  float* out = (float*)d_out;

  const int nrows  = in_sizes[0] / DD;       // 100000
  const int ne     = in_sizes[1] / 2;        // 400000
  const int ntiles = (nrows + TM - 1) / TM;  // 1563

  // ws layout (4B words), hbuf last (16B-aligned by construction):
  int* base = (int*)d_ws;
  unsigned short* wbf1 = (unsigned short*)base;            // 16384 bf16
  unsigned short* wbf2 = (unsigned short*)(base + 8192);   // 16384 bf16
  float* scsh  = (float*)(base + 16384);                   // 256
  int*   ofs   = base + 16384 + 256;                       // nrows+1
  int*   cur   = ofs + (nrows + 1);
  int*   csr   = cur + nrows;
  int*   bsum  = csr + ne;                                 // SB
  float* partial = (float*)(bsum + SB);                    // GRID_MLP*256 (1 MB)
  int*   cnt   = (int*)(partial + (size_t)GRID_MLP * 256); // nrows
  long long w_off = (long long)(cnt + nrows - base);
  w_off = (w_off + 3) & ~3LL;                              // 16B align
  unsigned short* hbuf = (unsigned short*)(base + w_off);  // nrows*DD bf16 (25.6 MB)

  const long long total8 = (long long)nrows * DD / 8;      // 1.6M
  const int agg_blocks  = (nrows * 16 + 255) / 256;        // 6250
  const int init_blocks = (nrows + 255) / 256;             // 391

  k_init <<<init_blocks,                  256, 0, stream>>>(w1, w2, wbf1, wbf2, cnt, nrows);
  k_hist <<<(ne + 255) / 256,             256, 0, stream>>>(eidx, cnt, ne);
  k_scan1<<<SB,                           256, 0, stream>>>(cnt, bsum, nrows);
  k_scan3<<<SB,                           256, 0, stream>>>(cnt, bsum, ofs, cur, nrows);
  k_fill <<<(ne + 255) / 256,             256, 0, stream>>>(eidx, cur, csr, ne);
  k_agg  <<<agg_blocks,                   256, 0, stream>>>(feat, ofs, csr, hbuf, nrows);
  k_mlp  <<<GRID_MLP,                     256, 0, stream>>>(hbuf, wbf1, b1, wbf2, b2,
                                                            partial, nrows, ntiles);
  k_stats<<<1,                            256, 0, stream>>>(partial, gamma, beta, scsh, nrows);
  k_bn   <<<(int)((total8 + 255) / 256),  256, 0, stream>>>(hbuf, out, scsh, total8);
}

// Round 7
// 229.810 us; speedup vs baseline: 5.3663x; 1.0716x over previous
//
#include <hip/hip_runtime.h>
#include <hip/hip_bf16.h>

#define DD 128
#define TM 64
#define LD 136        // padded LDS row stride (bf16 elems)
#define SB 128        // scan blocks
#define GRID_MLP 1024 // 4 blocks/CU persistent

typedef short bf16x8 __attribute__((ext_vector_type(8)));
typedef float f32x4  __attribute__((ext_vector_type(4)));

__device__ __forceinline__ unsigned short f2bf(float f) {
  unsigned int u = __float_as_uint(f);
  u += 0x7FFFu + ((u >> 16) & 1u);   // RNE
  return (unsigned short)(u >> 16);
}
__device__ __forceinline__ unsigned int pack2(float lo, float hi) {
  return (unsigned int)f2bf(lo) | ((unsigned int)f2bf(hi) << 16);
}
__device__ __forceinline__ float bf2f(unsigned short u) {
  union { unsigned int i; float f; } x; x.i = ((unsigned int)u) << 16; return x.f;
}

// init: zero cnt, convert weights fp32->bf16. One dispatch (replaces memset+prep).
__global__ __launch_bounds__(256) void k_init(const float* __restrict__ w1,
                                              const float* __restrict__ w2,
                                              unsigned short* __restrict__ wbf1,
                                              unsigned short* __restrict__ wbf2,
                                              int* __restrict__ cnt, int nrows) {
  int i = blockIdx.x * 256 + threadIdx.x;
  if (i < nrows) cnt[i] = 0;
  if (i < DD * DD) { wbf1[i] = f2bf(w1[i]); wbf2[i] = f2bf(w2[i]); }
}

// cnt[dst]++ per edge (int atomics, L2-resident)
__global__ __launch_bounds__(256) void k_hist(const int* __restrict__ ei, int* __restrict__ cnt,
                                              int ne) {
  int e = blockIdx.x * 256 + threadIdx.x;
  if (e < ne) atomicAdd(&cnt[ei[ne + e]], 1);
}

// scan stage 1: per-block chunk sums
__global__ __launch_bounds__(256) void k_scan1(const int* __restrict__ cnt,
                                               int* __restrict__ bsum, int n) {
  __shared__ int red[256];
  int b = blockIdx.x, t = threadIdx.x;
  int chunk = (n + SB - 1) / SB;
  int lo = b * chunk, hi = min(n, lo + chunk);
  int s = 0;
  for (int i = lo + t; i < hi; i += 256) s += cnt[i];
  red[t] = s;
  __syncthreads();
  for (int off = 128; off; off >>= 1) {
    if (t < off) red[t] += red[t + off];
    __syncthreads();
  }
  if (t == 0) bsum[b] = red[0];
}

// scan stage 2: each block redundantly scans bsum[SB] in LDS (folds old k_scan2),
// then exclusive-scans its chunk -> ofs, cur.
__global__ __launch_bounds__(256) void k_scan3(const int* __restrict__ cnt,
                                               const int* __restrict__ bsum,
                                               int* __restrict__ ofs, int* __restrict__ cur,
                                               int n) {
  __shared__ int red[256];
  __shared__ int sbs[SB];
  int b = blockIdx.x, t = threadIdx.x;

  // redundant exclusive scan of bsum[0..SB) in LDS
  int ov = (t < SB) ? bsum[t] : 0;
  if (t < SB) sbs[t] = ov;
  __syncthreads();
  for (int off = 1; off < SB; off <<= 1) {
    int v = (t < SB && t >= off) ? sbs[t - off] : 0;
    __syncthreads();
    if (t < SB) sbs[t] += v;
    __syncthreads();
  }
  if (t < SB) sbs[t] -= ov;   // exclusive
  __syncthreads();
  int base = sbs[b];
  if (b == SB - 1 && t == SB - 1) ofs[n] = sbs[t] + ov;  // total

  int chunk  = (n + SB - 1) / SB;
  int tchunk = (chunk + 255) / 256;
  int blo = b * chunk, bhi = min(n, blo + chunk);
  int lo = blo + t * tchunk, hi = min(bhi, lo + tchunk);
  int s = 0;
  for (int i = lo; i < hi; ++i) s += cnt[i];
  int mine = s;
  red[t] = s;
  __syncthreads();
  for (int off = 1; off < 256; off <<= 1) {
    int v = (t >= off) ? red[t - off] : 0;
    __syncthreads();
    red[t] += v;
    __syncthreads();
  }
  int run = base + red[t] - mine;
  for (int i = lo; i < hi; ++i) {
    int c = cnt[i];
    ofs[i] = run; cur[i] = run;
    run += c;
  }
}

// csr[pos] = src, pos = cur[dst]++
__global__ __launch_bounds__(256) void k_fill(const int* __restrict__ ei, int* __restrict__ cur,
                                              int* __restrict__ csr, int ne) {
  int e = blockIdx.x * 256 + threadIdx.x;
  if (e >= ne) return;
  int pos = atomicAdd(&cur[ei[ne + e]], 1);
  csr[pos] = ei[e];
}

// Dedicated high-occupancy gather: h = feat[row] + sum(neighbors), fp32 accum,
// RNE-pack to bf16 into agg (== hbuf). Demand-bandwidth-bound (~6.7 TB/s mixed).
__global__ __launch_bounds__(256) void k_agg(
    const float* __restrict__ feat, const int* __restrict__ ofs, const int* __restrict__ csr,
    unsigned short* __restrict__ agg, int nrows)
{
  int t = blockIdx.x * 256 + threadIdx.x;   // 16 threads per row, 8 cols each
  int row = t >> 4;
  if (row >= nrows) return;
  int c = (t & 15) * 8;
  const float* fr = feat + (long long)row * DD + c;
  float4 a0 = *reinterpret_cast<const float4*>(fr);
  float4 b0 = *reinterpret_cast<const float4*>(fr + 4);
  float4 a1 = make_float4(0.f, 0.f, 0.f, 0.f);
  float4 b1 = make_float4(0.f, 0.f, 0.f, 0.f);
  int o0 = ofs[row], o1 = ofs[row + 1];
  int j = o0;
  for (; j + 2 <= o1; j += 2) {
    const float* f0 = feat + (long long)csr[j]     * DD + c;
    const float* f1 = feat + (long long)csr[j + 1] * DD + c;
    float4 x0 = *reinterpret_cast<const float4*>(f0);
    float4 y0 = *reinterpret_cast<const float4*>(f0 + 4);
    float4 x1 = *reinterpret_cast<const float4*>(f1);
    float4 y1 = *reinterpret_cast<const float4*>(f1 + 4);
    a0.x += x0.x; a0.y += x0.y; a0.z += x0.z; a0.w += x0.w;
    b0.x += y0.x; b0.y += y0.y; b0.z += y0.z; b0.w += y0.w;
    a1.x += x1.x; a1.y += x1.y; a1.z += x1.z; a1.w += x1.w;
    b1.x += y1.x; b1.y += y1.y; b1.z += y1.z; b1.w += y1.w;
  }
  if (j < o1) {
    const float* f0 = feat + (long long)csr[j] * DD + c;
    float4 x0 = *reinterpret_cast<const float4*>(f0);
    float4 y0 = *reinterpret_cast<const float4*>(f0 + 4);
    a0.x += x0.x; a0.y += x0.y; a0.z += x0.z; a0.w += x0.w;
    b0.x += y0.x; b0.y += y0.y; b0.z += y0.z; b0.w += y0.w;
  }
  a0.x += a1.x; a0.y += a1.y; a0.z += a1.z; a0.w += a1.w;
  b0.x += b1.x; b0.y += b1.y; b0.z += b1.z; b0.w += b1.w;
  uint4 u;
  u.x = pack2(a0.x, a0.y); u.y = pack2(a0.z, a0.w);
  u.z = pack2(b0.x, b0.y); u.w = pack2(b0.z, b0.w);
  *reinterpret_cast<uint4*>(agg + (long long)row * DD + c) = u;
}

// Persistent fused MLP. Row-major bf16 hbuf == MFMA A-fragment layout, so GEMM1
// loads A directly from global (fully-sectored 16B/lane loads) — no LDS staging,
// 2 barriers/tile instead of 4. h2 transits LDS (layout change); epilogue packs
// via LDS for coalesced bf16 stores. BN stats register-accumulated per block.
__global__ __launch_bounds__(256) void k_mlp(
    unsigned short* hb,
    const unsigned short* __restrict__ wbf1, const float* __restrict__ b1,
    const unsigned short* __restrict__ wbf2, const float* __restrict__ b2,
    float* __restrict__ partial, int nrows, int ntiles)
{
  __shared__ unsigned short ldsP[TM * LD];   // epilogue pack buffer
  __shared__ unsigned short ldsH2[TM * LD];  // h2 buffer
  const int tid  = threadIdx.x;
  const int wave = tid >> 6, lane = tid & 63;
  const int q = lane >> 4, l16 = lane & 15;
  const int col0 = wave * 32;

  bf16x8 bw1[2][4], bw2[2][4];
  float bias1[2], bias2[2];
  for (int n = 0; n < 2; ++n) {
    int jc = col0 + n * 16 + l16;
    bias1[n] = b1[jc];
    bias2[n] = b2[jc];
    for (int kk = 0; kk < 4; ++kk) {
      bw1[n][kk] = *reinterpret_cast<const bf16x8*>(wbf1 + jc * DD + kk * 32 + q * 8);
      bw2[n][kk] = *reinterpret_cast<const bf16x8*>(wbf2 + jc * DD + kk * 32 + q * 8);
    }
  }

  const bf16x8 zf = {0, 0, 0, 0, 0, 0, 0, 0};
  float fs[2] = {0.f, 0.f}, fs2[2] = {0.f, 0.f};

  for (int tile = blockIdx.x; tile < ntiles; tile += GRID_MLP) {
    const int row0 = tile * TM;

    f32x4 acc[4][2];
    const f32x4 zero = {0.f, 0.f, 0.f, 0.f};
    for (int m = 0; m < 4; ++m) for (int n = 0; n < 2; ++n) acc[m][n] = zero;

    // GEMM1: A-fragments straight from global (row-major == fragment layout).
    #pragma unroll
    for (int kk = 0; kk < 4; ++kk) {
      bf16x8 aF[4];
      #pragma unroll
      for (int m = 0; m < 4; ++m) {
        int row = row0 + m * 16 + l16;
        aF[m] = (row < nrows)
            ? *reinterpret_cast<const bf16x8*>(hb + (long long)row * DD + kk * 32 + q * 8)
            : zf;
      }
      #pragma unroll
      for (int m = 0; m < 4; ++m)
        #pragma unroll
        for (int n = 0; n < 2; ++n)
          acc[m][n] = __builtin_amdgcn_mfma_f32_16x16x32_bf16(aF[m], bw1[n][kk], acc[m][n], 0, 0, 0);
    }

    // h2 = relu(acc + b1) -> ldsH2 (C/D: col=lane&15, row=quad*4+reg)
    for (int m = 0; m < 4; ++m)
      for (int n = 0; n < 2; ++n)
        for (int r = 0; r < 4; ++r) {
          float v = fmaxf(acc[m][n][r] + bias1[n], 0.f);
          ldsH2[(m * 16 + q * 4 + r) * LD + (col0 + n * 16 + l16)] = f2bf(v);
        }
    __syncthreads();   // S1: h2 visible; also protects ldsP reuse vs prev store

    for (int m = 0; m < 4; ++m) for (int n = 0; n < 2; ++n) acc[m][n] = zero;

    // GEMM2 from LDS
    #pragma unroll
    for (int kk = 0; kk < 4; ++kk) {
      bf16x8 aF[4];
      #pragma unroll
      for (int m = 0; m < 4; ++m)
        aF[m] = *reinterpret_cast<const bf16x8*>(&ldsH2[(m * 16 + l16) * LD + kk * 32 + q * 8]);
      #pragma unroll
      for (int m = 0; m < 4; ++m)
        #pragma unroll
        for (int n = 0; n < 2; ++n)
          acc[m][n] = __builtin_amdgcn_mfma_f32_16x16x32_bf16(aF[m], bw2[n][kk], acc[m][n], 0, 0, 0);
    }

    // Epilogue: relu+bias, accumulate BN stats in registers, pack bf16 -> ldsP.
    for (int m = 0; m < 4; ++m)
      for (int n = 0; n < 2; ++n) {
        int col = col0 + n * 16 + l16;
        for (int r = 0; r < 4; ++r) {
          int rl = m * 16 + q * 4 + r;
          float v = fmaxf(acc[m][n][r] + bias2[n], 0.f);
          ldsP[rl * LD + col] = f2bf(v);
          if (row0 + rl < nrows) { fs[n] += v; fs2[n] += v * v; }
        }
      }
    __syncthreads();   // S2: pack visible; also protects ldsH2 reuse vs next h2

    // Coalesced bf16 store of the tile back to hb (in-place over agg rows).
    for (int it = 0; it < 4; ++it) {
      int idx = it * 2048 + tid * 8;
      int r = idx >> 7, c = idx & 127;
      int row = row0 + r;
      if (row < nrows)
        *reinterpret_cast<uint4*>(hb + (long long)row * DD + c) =
            *reinterpret_cast<const uint4*>(&ldsP[r * LD + c]);
    }
  }

  // per-block partial store (non-atomic)
  for (int off = 16; off < 64; off <<= 1)
    for (int n = 0; n < 2; ++n) {
      fs[n]  += __shfl_xor(fs[n], off);
      fs2[n] += __shfl_xor(fs2[n], off);
    }
  if (q == 0) {
    float* pb = partial + (long long)blockIdx.x * 256;
    for (int n = 0; n < 2; ++n) {
      int col = col0 + n * 16 + l16;
      pb[col]       = fs[n];
      pb[128 + col] = fs2[n];
    }
  }
}

// Reduce per-block partials -> scale/shift. 128 blocks: block c owns columns
// (c, 128+c); parallel instead of one block reading 1 MB serially.
__global__ __launch_bounds__(256) void k_stats(const float* __restrict__ partial,
                                               const float* __restrict__ gamma,
                                               const float* __restrict__ beta,
                                               float* __restrict__ scsh, int nrows) {
  __shared__ float s0[256], s1[256];
  int c = blockIdx.x;   // 0..127
  int t = threadIdx.x;
  float a = 0.f, b = 0.f;
  for (int r = t; r < GRID_MLP; r += 256) {
    a += partial[(long long)r * 256 + c];
    b += partial[(long long)r * 256 + 128 + c];
  }
  s0[t] = a; s1[t] = b;
  __syncthreads();
  for (int off = 128; off; off >>= 1) {
    if (t < off) { s0[t] += s0[t + off]; s1[t] += s1[t + off]; }
    __syncthreads();
  }
  if (t == 0) {
    float mean = s0[0] / (float)nrows;
    float var  = fmaxf(s1[0] / (float)nrows - mean * mean, 0.f);
    float inv  = rsqrtf(var + 1e-5f);
    float sc   = gamma[c] * inv;
    scsh[c]       = sc;
    scsh[128 + c] = beta[c] - mean * sc;
  }
}

// BN apply: read bf16 hbuf (L3-warm), write fp32 out. One thread per 8 elems.
__global__ __launch_bounds__(256) void k_bn(const unsigned short* __restrict__ hbuf,
                                            float* __restrict__ out,
                                            const float* __restrict__ scsh,
                                            long long total8) {
  long long t = (long long)blockIdx.x * 256 + threadIdx.x;
  if (t >= total8) return;
  int c0 = (int)((t * 8) & 127);
  float4 sa = *reinterpret_cast<const float4*>(scsh + c0);
  float4 sb = *reinterpret_cast<const float4*>(scsh + c0 + 4);
  float4 ha = *reinterpret_cast<const float4*>(scsh + 128 + c0);
  float4 hb = *reinterpret_cast<const float4*>(scsh + 132 + c0);
  uint4 u = *reinterpret_cast<const uint4*>(hbuf + t * 8);
  float4 a, b;
  a.x = bf2f((unsigned short)(u.x & 0xFFFF)) * sa.x + ha.x;
  a.y = bf2f((unsigned short)(u.x >> 16))    * sa.y + ha.y;
  a.z = bf2f((unsigned short)(u.y & 0xFFFF)) * sa.z + ha.z;
  a.w = bf2f((unsigned short)(u.y >> 16))    * sa.w + ha.w;
  b.x = bf2f((unsigned short)(u.z & 0xFFFF)) * sb.x + hb.x;
  b.y = bf2f((unsigned short)(u.z >> 16))    * sb.y + hb.y;
  b.z = bf2f((unsigned short)(u.w & 0xFFFF)) * sb.z + hb.z;
  b.w = bf2f((unsigned short)(u.w >> 16))    * sb.w + hb.w;
  float* of = out + t * 8;
  *reinterpret_cast<float4*>(of)     = a;
  *reinterpret_cast<float4*>(of + 4) = b;
}

extern "C" void kernel_launch(void* const* d_in, const int* in_sizes, int n_in,
                              void* d_out, int out_size, void* d_ws, size_t ws_size,
                              hipStream_t stream) {
  const float* feat  = (const float*)d_in[0];
  const int*   eidx  = (const int*)d_in[1];
  const float* w1    = (const float*)d_in[2];
  const float* b1    = (const float*)d_in[3];
  const float* w2    = (const float*)d_in[4];
  const float* b2    = (const float*)d_in[5];
  const float* gamma = (const float*)d_in[6];
  const float* beta  = (const float*)d_in[7];
  float* out = (float*)d_out;

  const int nrows  = in_sizes[0] / DD;       // 100000
  const int ne     = in_sizes[1] / 2;        // 400000
  const int ntiles = (nrows + TM - 1) / TM;  // 1563

  // ws layout (4B words), hbuf last (16B-aligned by construction):
  int* base = (int*)d_ws;
  unsigned short* wbf1 = (unsigned short*)base;            // 16384 bf16
  unsigned short* wbf2 = (unsigned short*)(base + 8192);   // 16384 bf16
  float* scsh  = (float*)(base + 16384);                   // 256
  int*   ofs   = base + 16384 + 256;                       // nrows+1
  int*   cur   = ofs + (nrows + 1);
  int*   csr   = cur + nrows;
  int*   bsum  = csr + ne;                                 // SB
  float* partial = (float*)(bsum + SB);                    // GRID_MLP*256 (1 MB)
  int*   cnt   = (int*)(partial + (size_t)GRID_MLP * 256); // nrows
  long long w_off = (long long)(cnt + nrows - base);
  w_off = (w_off + 3) & ~3LL;                              // 16B align
  unsigned short* hbuf = (unsigned short*)(base + w_off);  // nrows*DD bf16 (25.6 MB)

  const long long total8 = (long long)nrows * DD / 8;      // 1.6M
  const int agg_blocks  = (nrows * 16 + 255) / 256;        // 6250
  const int init_blocks = (nrows + 255) / 256;             // 391

  k_init <<<init_blocks,                  256, 0, stream>>>(w1, w2, wbf1, wbf2, cnt, nrows);
  k_hist <<<(ne + 255) / 256,             256, 0, stream>>>(eidx, cnt, ne);
  k_scan1<<<SB,                           256, 0, stream>>>(cnt, bsum, nrows);
  k_scan3<<<SB,                           256, 0, stream>>>(cnt, bsum, ofs, cur, nrows);
  k_fill <<<(ne + 255) / 256,             256, 0, stream>>>(eidx, cur, csr, ne);
  k_agg  <<<agg_blocks,                   256, 0, stream>>>(feat, ofs, csr, hbuf, nrows);
  k_mlp  <<<GRID_MLP,                     256, 0, stream>>>(hbuf, wbf1, b1, wbf2, b2,
                                                            partial, nrows, ntiles);
  k_stats<<<128,                          256, 0, stream>>>(partial, gamma, beta, scsh, nrows);
  k_bn   <<<(int)((total8 + 255) / 256),  256, 0, stream>>>(hbuf, out, scsh, total8);
}